// Round 4
// baseline (235.743 us; speedup 1.0000x reference)
//
#include <hip/hip_runtime.h>

// LSTM-cell (h0=c0=0) + Linear, fused.
// gates = x @ W_ih^T + (b_ih+b_hh); ref split order: i|f|g|o (50 each).
// f unused (c_prev=0): c = sig(i)*tanh(g); h = sig(o)*tanh(c)
// out = h @ W_lin^T + b_lin.  x: [65536,1024] f32, out: [65536,1024] f32.
// Memory-bound (512MB HBM => ~81us floor). MFMA 16x16x16f16 canonical layout,
// fp32 accumulation. Packed gates: i->0-49, g->50-99, o->100-149, pad->160.
// NOTE round-3 bug: o-block offset was +100 (OOB read past W_ih's 200 rows);
// correct offset is +50 for BOTH g and o blocks (skip the 50-row f block).

typedef _Float16 f16;
typedef f16 f16x4 __attribute__((ext_vector_type(4)));
typedef float f32x4 __attribute__((ext_vector_type(4)));

#define W1_ELEMS (160 * 1024)
#define W2_ELEMS (1024 * 64)
#define G_PACK 160

__device__ f16 g_W1[W1_ELEMS];     // [160][1024] packed gate rows, f16
__device__ f16 g_W2[W2_ELEMS];     // [1024][64]  W_lin rows, K padded 50->64
__device__ float g_bias[G_PACK];   // packed b_ih+b_hh

// packed row -> original gate row: i(0..49)->same, g(50..99)->+50 (orig 100..149),
// o(100..149)->+50 (orig 150..199), pad(150..159)->-1
__device__ __forceinline__ int pack_map(int j) {
    return (j < 50) ? j : (j < 150) ? (j + 50) : -1;
}

// ---- prep: convert + pack weights (runs every call; deterministic) ----
__global__ __launch_bounds__(256) void prep_kernel(
    const float* __restrict__ W_ih, const float* __restrict__ b_ih,
    const float* __restrict__ b_hh, const float* __restrict__ W_lin)
{
    int idx = blockIdx.x * 256 + threadIdx.x;
    if (idx < W1_ELEMS) {
        int j = idx >> 10, k = idx & 1023;
        int oj = pack_map(j);
        float v = (oj >= 0) ? W_ih[oj * 1024 + k] : 0.f;
        g_W1[idx] = (f16)v;
    } else if (idx < W1_ELEMS + W2_ELEMS) {
        int i2 = idx - W1_ELEMS;
        int n = i2 >> 6, k = i2 & 63;          // W2: [1024][64]
        float v = (k < 50) ? W_lin[n * 50 + k] : 0.f;
        g_W2[i2] = (f16)v;
    } else if (idx < W1_ELEMS + W2_ELEMS + G_PACK) {
        int i3 = idx - (W1_ELEMS + W2_ELEMS);
        int oj = pack_map(i3);
        g_bias[i3] = (oj >= 0) ? (b_ih[oj] + b_hh[oj]) : 0.f;
    }
}

// ---- fused main kernel: 64 rows per block, grid = 65536/64 = 1024 ----
__global__ __launch_bounds__(256) void lstm_fused(
    const float* __restrict__ x, const float* __restrict__ blin,
    float* __restrict__ out)
{
    // union: phase1 x double-buffer [2][64][136] f16 (34816B)
    //        phase1.5 gates [64][160] f32 (40960B)
    __shared__ __align__(16) char smem[64 * 160 * 4];
    __shared__ __align__(16) f16 h_sm[64][72];   // 144B row stride (16B-mult)

    f16* xs = (f16*)smem;
    float* gs = (float*)smem;

    const int tid = threadIdx.x;
    const int lane = tid & 63;
    const int wv = tid >> 6;                 // wave id 0..3
    const int lcol = lane & 15;              // MFMA i/j index
    const int lk4 = (lane >> 4) << 2;        // k offset 0,4,8,12
    const int rsub = (lane >> 4) << 2;       // C/D row group 0,4,8,12
    const long row0 = (long)blockIdx.x * 64;

    // gate tile ownership: w0:{0,4,8} w1:{1,5,9} w2:{2,6} w3:{3,7}
    const int ntile = (wv < 2) ? 3 : 2;

    f32x4 acc[3][4];
    #pragma unroll
    for (int a = 0; a < 3; ++a)
        #pragma unroll
        for (int b = 0; b < 4; ++b)
            acc[a][b] = (f32x4){0.f, 0.f, 0.f, 0.f};

    // ---------------- phase 1: gates = x @ W1^T (K=1024, chunks of 128) ----
    const float* xblk = x + row0 * 1024;
    for (int kc = 0; kc < 8; ++kc) {
        f16* xbuf = xs + (kc & 1) * (64 * 136);
        {   // stage: 64x128 f32 -> f16 LDS; 2048 float4 loads, 8/thread
            const float* src = xblk + kc * 128;
            #pragma unroll
            for (int i = 0; i < 8; ++i) {
                int v = tid + i * 256;       // 0..2047
                int r = v >> 5;              // row 0..63
                int c = (v & 31) << 2;       // col 0..124 step 4
                float4 q = *(const float4*)(src + (long)r * 1024 + c);
                f16x4 hq = { (f16)q.x, (f16)q.y, (f16)q.z, (f16)q.w };
                *(f16x4*)(xbuf + r * 136 + c) = hq;
            }
        }
        __syncthreads();  // dbuf: single barrier per chunk is race-free
        const f16* w1c = g_W1 + kc * 128;
        #pragma unroll
        for (int ks = 0; ks < 8; ++ks) {     // 8 x K=16 steps per 128-chunk
            f16x4 afr[4];
            #pragma unroll
            for (int rt = 0; rt < 4; ++rt)
                afr[rt] = *(const f16x4*)(xbuf + (rt * 16 + lcol) * 136 + ks * 16 + lk4);
            #pragma unroll
            for (int gi = 0; gi < 3; ++gi) { // fixed bound + uniform guard: no scratch
                if (gi < ntile) {
                    int gt = wv + gi * 4;
                    f16x4 bfr = *(const f16x4*)(w1c + (long)(gt * 16 + lcol) * 1024 + ks * 16 + lk4);
                    #pragma unroll
                    for (int rt = 0; rt < 4; ++rt)
                        acc[gi][rt] = __builtin_amdgcn_mfma_f32_16x16x16f16(afr[rt], bfr, acc[gi][rt], 0, 0, 0);
                }
            }
        }
    }
    __syncthreads();

    // ---------------- phase 1.5: gates(+bias) -> LDS, cross-wave exchange ----
    #pragma unroll
    for (int gi = 0; gi < 3; ++gi) {
        if (gi < ntile) {
            int gt = wv + gi * 4;
            float bb = g_bias[gt * 16 + lcol];
            #pragma unroll
            for (int rt = 0; rt < 4; ++rt) {
                #pragma unroll
                for (int r = 0; r < 4; ++r)
                    gs[(rt * 16 + rsub + r) * 160 + gt * 16 + lcol] = acc[gi][rt][r] + bb;
            }
        }
    }
    __syncthreads();

    // ---------------- nonlinearity: h = sig(o)*tanh(sig(i)*tanh(g)) ----
    #pragma unroll
    for (int i = 0; i < 16; ++i) {
        int e = tid + i * 256;               // covers 64x64 h tile (cols 50..63 = 0)
        int r = e >> 6, c = e & 63;
        float hv = 0.f;
        if (c < 50) {
            float iv = gs[r * 160 + c];
            float gv = gs[r * 160 + 50 + c];
            float ov = gs[r * 160 + 100 + c];
            float cv = tanhf(gv) / (1.f + __expf(-iv));
            hv = tanhf(cv) / (1.f + __expf(-ov));
        }
        h_sm[r][c] = (f16)hv;
    }
    __syncthreads();

    // ---------------- phase 2: out = h @ W2^T + b_lin (K=64) ----
    f16x4 ha[4][4];
    #pragma unroll
    for (int rt = 0; rt < 4; ++rt)
        #pragma unroll
        for (int ks = 0; ks < 4; ++ks)
            ha[rt][ks] = *(const f16x4*)(&h_sm[rt * 16 + lcol][ks * 16 + lk4]);

    const int col0 = wv * 256;               // each wave owns 256 output cols
    float* outb = out + row0 * 1024;
    #pragma unroll 2
    for (int n2 = 0; n2 < 16; ++n2) {
        int cb = col0 + n2 * 16;
        float bl = blin[cb + lcol];
        const f16* w2p = g_W2 + (long)(cb + lcol) * 64;
        f16x4 bf[4];
        #pragma unroll
        for (int ks = 0; ks < 4; ++ks)
            bf[ks] = *(const f16x4*)(w2p + ks * 16 + lk4);
        #pragma unroll
        for (int rt = 0; rt < 4; ++rt) {
            f32x4 o = { bl, bl, bl, bl };
            #pragma unroll
            for (int ks = 0; ks < 4; ++ks)
                o = __builtin_amdgcn_mfma_f32_16x16x16f16(ha[rt][ks], bf[ks], o, 0, 0, 0);
            int rb = rt * 16 + rsub;
            #pragma unroll
            for (int r = 0; r < 4; ++r)
                outb[(long)(rb + r) * 1024 + cb + lcol] = o[r];
        }
    }
}

extern "C" void kernel_launch(void* const* d_in, const int* in_sizes, int n_in,
                              void* d_out, int out_size, void* d_ws, size_t ws_size,
                              hipStream_t stream) {
    const float* x     = (const float*)d_in[0];
    const float* W_ih  = (const float*)d_in[1];
    // d_in[2] = W_hh — provably unused (h_prev = 0)
    const float* b_ih  = (const float*)d_in[3];
    const float* b_hh  = (const float*)d_in[4];
    const float* W_lin = (const float*)d_in[5];
    const float* b_lin = (const float*)d_in[6];
    float* out = (float*)d_out;

    int prep_total = W1_ELEMS + W2_ELEMS + G_PACK;
    prep_kernel<<<(prep_total + 255) / 256, 256, 0, stream>>>(
        W_ih, b_ih, b_hh, W_lin);

    lstm_fused<<<1024, 256, 0, stream>>>(x, b_lin, out);
}

// Round 5
// 224.037 us; speedup vs baseline: 1.0522x; 1.0522x over previous
//
#include <hip/hip_runtime.h>

// LSTM-cell (h0=c0=0) + Linear, fused.
// gates = x @ W_ih^T + (b_ih+b_hh); ref split i|f|g|o (50 each), f unused.
// h = sig(o)*tanh(sig(i)*tanh(g)); out = h @ W_lin^T + b_lin.
// x: [65536,1024] f32 -> out: [65536,1024] f32. Memory-bound target ~81us.
// R5 changes vs R4 (260us, occ 28.6%, latency-bound):
//  - LDS 50176->40960B: h detours through regs so h_sm overlays dead gate buf
//    => exactly 4 blocks/CU (was 3), 16 waves/CU.
//  - T14 async-stage split: issue chunk kc+1 global loads (regs) before
//    compute(kc); convert+write at top of next iter. 1 barrier/chunk kept.
//  - __launch_bounds__(256,4) pins VGPR<=128 for 4 waves/SIMD.

typedef _Float16 f16;
typedef f16 f16x4 __attribute__((ext_vector_type(4)));
typedef float f32x4 __attribute__((ext_vector_type(4)));

#define W1_ELEMS (160 * 1024)
#define W2_ELEMS (1024 * 64)
#define G_PACK 160

__device__ f16 g_W1[W1_ELEMS];     // [160][1024] packed gate rows, f16
__device__ f16 g_W2[W2_ELEMS];     // [1024][64]  W_lin rows, K padded 50->64
__device__ float g_bias[G_PACK];   // packed b_ih+b_hh

// packed row -> original gate row: i(0..49)->same, g/o(50..149)->+50, pad->-1
__device__ __forceinline__ int pack_map(int j) {
    return (j < 50) ? j : (j < 150) ? (j + 50) : -1;
}

__global__ __launch_bounds__(256) void prep_kernel(
    const float* __restrict__ W_ih, const float* __restrict__ b_ih,
    const float* __restrict__ b_hh, const float* __restrict__ W_lin)
{
    int idx = blockIdx.x * 256 + threadIdx.x;
    if (idx < W1_ELEMS) {
        int j = idx >> 10, k = idx & 1023;
        int oj = pack_map(j);
        g_W1[idx] = (f16)((oj >= 0) ? W_ih[oj * 1024 + k] : 0.f);
    } else if (idx < W1_ELEMS + W2_ELEMS) {
        int i2 = idx - W1_ELEMS;
        int n = i2 >> 6, k = i2 & 63;
        g_W2[i2] = (f16)((k < 50) ? W_lin[n * 50 + k] : 0.f);
    } else if (idx < W1_ELEMS + W2_ELEMS + G_PACK) {
        int i3 = idx - (W1_ELEMS + W2_ELEMS);
        int oj = pack_map(i3);
        g_bias[i3] = (oj >= 0) ? (b_ih[oj] + b_hh[oj]) : 0.f;
    }
}

// ---- fused main kernel: 64 rows/block, grid 1024 = 4 blocks/CU resident ----
__global__ __launch_bounds__(256, 4) void lstm_fused(
    const float* __restrict__ x, const float* __restrict__ blin,
    float* __restrict__ out)
{
    // one 40960B union:
    //   phase1:  x dbuf [2][64][136] f16 = 34816B
    //   phase1.5: gates [64][160] f32   = 40960B
    //   phase2:  h [64][72] f16         =  9216B
    __shared__ __align__(16) char smem[40960];
    f16*   xs = (f16*)smem;
    float* gs = (float*)smem;
    f16*   hs = (f16*)smem;

    const int tid  = threadIdx.x;
    const int lane = tid & 63;
    const int wv   = tid >> 6;               // wave 0..3
    const int lcol = lane & 15;              // MFMA i/j index
    const int lk4  = (lane >> 4) << 2;       // k offset 0,4,8,12
    const int rsub = (lane >> 4) << 2;       // C/D row group 0,4,8,12
    const long row0 = (long)blockIdx.x * 64;

    // gate tile ownership: w0:{0,4,8} w1:{1,5,9} w2:{2,6} w3:{3,7}
    const int ntile = (wv < 2) ? 3 : 2;

    f32x4 acc[3][4];
    #pragma unroll
    for (int a = 0; a < 3; ++a)
        #pragma unroll
        for (int b = 0; b < 4; ++b)
            acc[a][b] = (f32x4){0.f, 0.f, 0.f, 0.f};

    const float* xblk = x + row0 * 1024;

    // T14: per-chunk staging registers (8 float4 = 32 VGPR)
    float4 q[8];
    #pragma unroll
    for (int i = 0; i < 8; ++i) {            // issue chunk 0 loads
        int v = tid + i * 256, r = v >> 5, c = (v & 31) << 2;
        q[i] = *(const float4*)(xblk + (long)r * 1024 + c);
    }

    // ------------- phase 1: gates = x @ W1^T (K=1024, 8 chunks of 128) -----
    for (int kc = 0; kc < 8; ++kc) {
        f16* xbuf = xs + (kc & 1) * (64 * 136);
        #pragma unroll
        for (int i = 0; i < 8; ++i) {        // convert + LDS write (vmcnt drain)
            int v = tid + i * 256, r = v >> 5, c = (v & 31) << 2;
            f16x4 hq = { (f16)q[i].x, (f16)q[i].y, (f16)q[i].z, (f16)q[i].w };
            *(f16x4*)(xbuf + r * 136 + c) = hq;
        }
        __syncthreads();
        if (kc < 7) {                        // issue next chunk; overlaps MFMA
            const float* src = xblk + (kc + 1) * 128;
            #pragma unroll
            for (int i = 0; i < 8; ++i) {
                int v = tid + i * 256, r = v >> 5, c = (v & 31) << 2;
                q[i] = *(const float4*)(src + (long)r * 1024 + c);
            }
        }
        const f16* w1c = g_W1 + kc * 128;
        #pragma unroll
        for (int ks = 0; ks < 8; ++ks) {     // 8 x K=16 steps per chunk
            f16x4 afr[4];
            #pragma unroll
            for (int rt = 0; rt < 4; ++rt)
                afr[rt] = *(const f16x4*)(xbuf + (rt * 16 + lcol) * 136 + ks * 16 + lk4);
            #pragma unroll
            for (int gi = 0; gi < 3; ++gi) { // fixed bound + uniform guard
                if (gi < ntile) {
                    int gt = wv + gi * 4;
                    f16x4 bfr = *(const f16x4*)(w1c + (long)(gt * 16 + lcol) * 1024 + ks * 16 + lk4);
                    #pragma unroll
                    for (int rt = 0; rt < 4; ++rt)
                        acc[gi][rt] = __builtin_amdgcn_mfma_f32_16x16x16f16(afr[rt], bfr, acc[gi][rt], 0, 0, 0);
                }
            }
        }
        __syncthreads();                     // xs buf reused / gs overlay next
    }

    // ------------- phase 1.5: gates(+bias) -> LDS exchange ------------------
    #pragma unroll
    for (int gi = 0; gi < 3; ++gi) {
        if (gi < ntile) {
            int gt = wv + gi * 4;
            float bb = g_bias[gt * 16 + lcol];
            #pragma unroll
            for (int rt = 0; rt < 4; ++rt)
                #pragma unroll
                for (int r = 0; r < 4; ++r)
                    gs[(rt * 16 + rsub + r) * 160 + gt * 16 + lcol] = acc[gi][rt][r] + bb;
        }
    }
    __syncthreads();

    // ------------- nonlinearity -> h in regs (gs still live) ---------------
    float hreg[16];
    #pragma unroll
    for (int i = 0; i < 16; ++i) {
        int e = tid + i * 256, r = e >> 6, c = e & 63;
        float hv = 0.f;
        if (c < 50) {
            float iv = gs[r * 160 + c];
            float gv = gs[r * 160 + 50 + c];
            float ov = gs[r * 160 + 100 + c];
            float cv = tanhf(gv) / (1.f + __expf(-iv));
            hv = tanhf(cv) / (1.f + __expf(-ov));
        }
        hreg[i] = hv;
    }
    __syncthreads();                         // all gs reads done

    #pragma unroll
    for (int i = 0; i < 16; ++i) {           // h -> LDS (overwrites gs region)
        int e = tid + i * 256, r = e >> 6, c = e & 63;
        hs[r * 72 + c] = (f16)hreg[i];
    }
    __syncthreads();

    // ------------- phase 2: out = h @ W2^T + b_lin (K=64) -------------------
    f16x4 ha[4][4];
    #pragma unroll
    for (int rt = 0; rt < 4; ++rt)
        #pragma unroll
        for (int ks = 0; ks < 4; ++ks)
            ha[rt][ks] = *(const f16x4*)(hs + (rt * 16 + lcol) * 72 + ks * 16 + lk4);

    const int col0 = wv * 256;               // each wave owns 256 output cols
    float* outb = out + row0 * 1024;
    #pragma unroll 2
    for (int n2 = 0; n2 < 16; ++n2) {
        int cb = col0 + n2 * 16;
        float bl = blin[cb + lcol];
        const f16* w2p = g_W2 + (long)(cb + lcol) * 64;
        f16x4 bf[4];
        #pragma unroll
        for (int ks = 0; ks < 4; ++ks)
            bf[ks] = *(const f16x4*)(w2p + ks * 16 + lk4);
        #pragma unroll
        for (int rt = 0; rt < 4; ++rt) {
            f32x4 o = { bl, bl, bl, bl };
            #pragma unroll
            for (int ks = 0; ks < 4; ++ks)
                o = __builtin_amdgcn_mfma_f32_16x16x16f16(ha[rt][ks], bf[ks], o, 0, 0, 0);
            int rb = rt * 16 + rsub;
            #pragma unroll
            for (int r = 0; r < 4; ++r)
                outb[(long)(rb + r) * 1024 + cb + lcol] = o[r];
        }
    }
}

extern "C" void kernel_launch(void* const* d_in, const int* in_sizes, int n_in,
                              void* d_out, int out_size, void* d_ws, size_t ws_size,
                              hipStream_t stream) {
    const float* x     = (const float*)d_in[0];
    const float* W_ih  = (const float*)d_in[1];
    // d_in[2] = W_hh — provably unused (h_prev = 0)
    const float* b_ih  = (const float*)d_in[3];
    const float* b_hh  = (const float*)d_in[4];
    const float* W_lin = (const float*)d_in[5];
    const float* b_lin = (const float*)d_in[6];
    float* out = (float*)d_out;

    int prep_total = W1_ELEMS + W2_ELEMS + G_PACK;
    prep_kernel<<<(prep_total + 255) / 256, 256, 0, stream>>>(
        W_ih, b_ih, b_hh, W_lin);

    lstm_fused<<<1024, 256, 0, stream>>>(x, b_lin, out);
}

// Round 6
// 207.095 us; speedup vs baseline: 1.1383x; 1.0818x over previous
//
#include <hip/hip_runtime.h>

// LSTM-cell (h0=c0=0) + Linear, fused.  out = Lin(h(x @ W_ih^T + b)), f-gate dead.
// x: [65536,1024] f32 -> out: [65536,1024] f32. HBM floor ~81us (512MB @6.3TB/s).
// R6 structure (vs R5 245us latency-bound, 17 barriers, lockstep waves):
//  - wave-row decomposition: wave owns 16 rows; A-frags straight from global
//    (no x LDS staging, no convert stage, no x redundancy), phase1 barrier-free.
//  - W1 pre-swizzled [ks32][gt][lane] f16x8 -> every B-frag load = 1KB coalesced L2 hit.
//  - phase2 operand swap (A=W2,B=h): lane owns 4 consecutive out-cols -> float4 stores.
//  - gate exchange via rotation-swizzled gs[64][160] f32 (40960B, 4 blocks/CU),
//    2-way max bank access both sides; 3 barriers total.
// MFMA 16x16x32_f16: k-map (lane,j)->8*(lane>>4)+j used identically for A and B
// (consistent-bijection invariance => correct regardless of HW k-order; D-layout
// col=lane&15,row=4*(lane>>4)+r empirically pinned in R4).

typedef _Float16 f16;
typedef f16 f16x8 __attribute__((ext_vector_type(8)));
typedef float f32x4 __attribute__((ext_vector_type(4)));

#define W1S_ELEMS (32 * 10 * 64)   // f16x8 units: [ks32][gt][lane]
#define W2S_ELEMS (64 * 2 * 64)    // f16x8 units: [ct][ks2][lane]

__device__ f16x8 g_w1s[W1S_ELEMS];
__device__ f16x8 g_w2s[W2S_ELEMS];
__device__ float g_bias[160];

// packed gate row -> original W_ih row: i(0..49)->same, g/o(50..149)->+50 (skip f)
__device__ __forceinline__ int pack_map(int j) {
    return (j < 50) ? j : (j < 150) ? (j + 50) : -1;
}

__global__ __launch_bounds__(256) void prep_kernel(
    const float* __restrict__ W_ih, const float* __restrict__ b_ih,
    const float* __restrict__ b_hh, const float* __restrict__ W_lin)
{
    int idx = blockIdx.x * 256 + threadIdx.x;
    if (idx < W1S_ELEMS) {
        int lane = idx & 63, rest = idx >> 6;
        int gt = rest % 10, ks = rest / 10;
        int prow = gt * 16 + (lane & 15);
        int oj = pack_map(prow);
        int k0 = ks * 32 + ((lane >> 4) << 3);
        f16x8 v;
        #pragma unroll
        for (int j = 0; j < 8; ++j)
            v[j] = (f16)((oj >= 0) ? W_ih[oj * 1024 + k0 + j] : 0.f);
        g_w1s[idx] = v;
    } else if (idx < W1S_ELEMS + W2S_ELEMS) {
        int i2 = idx - W1S_ELEMS;
        int lane = i2 & 63, rest = i2 >> 6;
        int ks = rest & 1, ct = rest >> 1;
        int ocol = ct * 16 + (lane & 15);        // out column
        int k0 = ks * 32 + ((lane >> 4) << 3);
        f16x8 v;
        #pragma unroll
        for (int j = 0; j < 8; ++j) {
            int k = k0 + j;
            v[j] = (f16)((k < 50) ? W_lin[ocol * 50 + k] : 0.f);
        }
        g_w2s[i2] = v;
    } else if (idx < W1S_ELEMS + W2S_ELEMS + 160) {
        int i3 = idx - (W1S_ELEMS + W2S_ELEMS);
        int oj = pack_map(i3);
        g_bias[i3] = (oj >= 0) ? (b_ih[oj] + b_hh[oj]) : 0.f;
    }
}

// rotation swizzle: free (<=2-way) banks for both gate writes and nonlin reads
__device__ __forceinline__ int gaddr(int row, int col) {
    int c = col + ((row & 15) << 2);
    if (c >= 160) c -= 160;
    return row * 160 + c;
}

__device__ __forceinline__ float fast_tanh(float v) {
    float t = __expf(-2.f * v);            // |gate| << 44 => no overflow
    return (1.f - t) / (1.f + t);
}

__global__ __launch_bounds__(256, 4) void lstm_fused(
    const float* __restrict__ x, const float* __restrict__ blin,
    float* __restrict__ out)
{
    __shared__ __align__(16) float gs[64 * 160];   // 40960B; hs overlays after barrier
    f16* hs = (f16*)gs;                            // [64][72] f16 (stride 144B, 16B-mult)

    const int tid  = threadIdx.x;
    const int lane = tid & 63;
    const int wv   = tid >> 6;
    const int lcol = lane & 15;
    const int l4   = lane >> 4;
    const long row0 = (long)blockIdx.x * 64;
    const int wrow = wv * 16;                      // wave's 16-row slice

    // ---------- phase 1 (barrier-free): gates for 16 rows x 160 gate-cols ----
    const float* xrow = x + (row0 + wrow + lcol) * 1024 + l4 * 8;

    f32x4 acc[10];
    #pragma unroll
    for (int g = 0; g < 10; ++g) acc[g] = (f32x4){0.f, 0.f, 0.f, 0.f};

    for (int ks = 0; ks < 32; ++ks) {
        float4 xa = *(const float4*)(xrow + ks * 32);
        float4 xb = *(const float4*)(xrow + ks * 32 + 4);
        f16x8 af = { (f16)xa.x, (f16)xa.y, (f16)xa.z, (f16)xa.w,
                     (f16)xb.x, (f16)xb.y, (f16)xb.z, (f16)xb.w };
        const f16x8* wb = g_w1s + ks * 640 + lane;
        #pragma unroll
        for (int g = 0; g < 10; ++g) {
            f16x8 bf = wb[g * 64];
            acc[g] = __builtin_amdgcn_mfma_f32_16x16x32_f16(af, bf, acc[g], 0, 0, 0);
        }
    }

    // gates(+bias) -> swizzled LDS.  D: row=4*l4+r (x-row), col=g*16+lcol
    #pragma unroll
    for (int g = 0; g < 10; ++g) {
        float bb = g_bias[g * 16 + lcol];
        #pragma unroll
        for (int r = 0; r < 4; ++r)
            gs[gaddr(wrow + l4 * 4 + r, g * 16 + lcol)] = acc[g][r] + bb;
    }
    __syncthreads();

    // ---------- nonlinearity: thread -> (row=tid>>2, 13 cols) -----------------
    const int nrow = tid >> 2, sub = tid & 3;
    const int c0 = sub * 13;                       // covers cols 0..51
    float hreg[13];
    #pragma unroll
    for (int j = 0; j < 13; ++j) {
        int c = c0 + j;
        float hv = 0.f;
        if (c < 50) {
            float iv = gs[gaddr(nrow, c)];
            float gv = gs[gaddr(nrow, 50 + c)];
            float ov = gs[gaddr(nrow, 100 + c)];
            float cv = fast_tanh(gv) / (1.f + __expf(-iv));
            hv = fast_tanh(cv) / (1.f + __expf(-ov));
        }
        hreg[j] = hv;
    }
    __syncthreads();                               // gs reads done before overlay

    #pragma unroll
    for (int j = 0; j < 13; ++j)
        hs[nrow * 72 + c0 + j] = (f16)hreg[j];
    if (sub == 3) {                                // zero-fill k-pad cols 52..63
        #pragma unroll
        for (int c = 52; c < 64; ++c) hs[nrow * 72 + c] = (f16)0.f;
    }
    __syncthreads();

    // ---------- phase 2 (barrier-free): out = h @ W2^T + b_lin ---------------
    // swap: A=W2 (M=out-cols), B=h (N=rows) => lane stores float4 of 4 cols
    const int hrow = wrow + lcol;
    f16x8 bh0 = *(const f16x8*)(hs + hrow * 72 + l4 * 8);
    f16x8 bh1 = *(const f16x8*)(hs + hrow * 72 + 32 + l4 * 8);
    float* orow = out + (row0 + hrow) * 1024;

    #pragma unroll 4
    for (int ct = 0; ct < 64; ++ct) {
        float4 bl = *(const float4*)(blin + ct * 16 + l4 * 4);
        f32x4 o = { bl.x, bl.y, bl.z, bl.w };
        const f16x8* w2b = g_w2s + ct * 128 + lane;
        o = __builtin_amdgcn_mfma_f32_16x16x32_f16(w2b[0],  bh0, o, 0, 0, 0);
        o = __builtin_amdgcn_mfma_f32_16x16x32_f16(w2b[64], bh1, o, 0, 0, 0);
        *(float4*)(orow + ct * 16 + l4 * 4) = *(float4*)&o;
    }
}

extern "C" void kernel_launch(void* const* d_in, const int* in_sizes, int n_in,
                              void* d_out, int out_size, void* d_ws, size_t ws_size,
                              hipStream_t stream) {
    const float* x     = (const float*)d_in[0];
    const float* W_ih  = (const float*)d_in[1];
    // d_in[2] = W_hh — provably unused (h_prev = 0)
    const float* b_ih  = (const float*)d_in[3];
    const float* b_hh  = (const float*)d_in[4];
    const float* W_lin = (const float*)d_in[5];
    const float* b_lin = (const float*)d_in[6];
    float* out = (float*)d_out;

    int prep_total = W1S_ELEMS + W2S_ELEMS + 160;
    prep_kernel<<<(prep_total + 255) / 256, 256, 0, stream>>>(
        W_ih, b_ih, b_hh, W_lin);

    lstm_fused<<<1024, 256, 0, stream>>>(x, b_lin, out);
}

// Round 7
// 187.195 us; speedup vs baseline: 1.2593x; 1.1063x over previous
//
#include <hip/hip_runtime.h>

// LSTM-cell (h0=c0=0) + Linear, fused.  out = Lin(h(x @ W_ih^T + b)), f-gate dead.
// x: [65536,1024] f32 -> out: [65536,1024] f32. HBM floor ~81us (512MB @6.3TB/s).
// R7 (vs R6 234us: all pipes idle, VGPR=52 => zero load pipelining, serial
// latency ~576 loads x ~800cy): phase 1 rebuilt as DMA-staged GEMM:
//  - global_load_lds (async, zero-VGPR, deep queue) stages x (8KB f32) and
//    W1 chunk (10KB f16) per 32-K step, double-buffered, 2-deep prefetch.
//  - counted per-wave vmcnt (never 0 mid-loop) + raw s_barrier (NOT
//    __syncthreads, which drains vmcnt) => loads ride across barriers.
//  - x LDS image source-swizzled u^=(r&7) (linear DMA dest + inv-swz source
//    + swz read) => A-frag ds_reads bank-balanced; W1 reads contiguous 1KB.
//  - LDS 36KB phase-1 union 40KB gates => 4 blocks/CU kept.
// Phase 1.5 (swizzled gate exchange), nonlin, phase 2 verbatim from R6 (passed).

typedef _Float16 f16;
typedef f16 f16x8 __attribute__((ext_vector_type(8)));
typedef float f32x4 __attribute__((ext_vector_type(4)));

#define W1S_ELEMS (32 * 10 * 64)   // f16x8 units: [ks32][gt][lane]
#define W2S_ELEMS (64 * 2 * 64)    // f16x8 units: [ct][ks2][lane]

__device__ f16x8 g_w1s[W1S_ELEMS];
__device__ f16x8 g_w2s[W2S_ELEMS];
__device__ float g_bias[160];

__device__ __forceinline__ int pack_map(int j) {
    return (j < 50) ? j : (j < 150) ? (j + 50) : -1;   // skip dead f-gate rows
}

__global__ __launch_bounds__(256) void prep_kernel(
    const float* __restrict__ W_ih, const float* __restrict__ b_ih,
    const float* __restrict__ b_hh, const float* __restrict__ W_lin)
{
    int idx = blockIdx.x * 256 + threadIdx.x;
    if (idx < W1S_ELEMS) {
        int lane = idx & 63, rest = idx >> 6;
        int gt = rest % 10, ks = rest / 10;
        int prow = gt * 16 + (lane & 15);
        int oj = pack_map(prow);
        int k0 = ks * 32 + ((lane >> 4) << 3);
        f16x8 v;
        #pragma unroll
        for (int j = 0; j < 8; ++j)
            v[j] = (f16)((oj >= 0) ? W_ih[oj * 1024 + k0 + j] : 0.f);
        g_w1s[idx] = v;
    } else if (idx < W1S_ELEMS + W2S_ELEMS) {
        int i2 = idx - W1S_ELEMS;
        int lane = i2 & 63, rest = i2 >> 6;
        int ks = rest & 1, ct = rest >> 1;
        int ocol = ct * 16 + (lane & 15);
        int k0 = ks * 32 + ((lane >> 4) << 3);
        f16x8 v;
        #pragma unroll
        for (int j = 0; j < 8; ++j) {
            int k = k0 + j;
            v[j] = (f16)((k < 50) ? W_lin[ocol * 50 + k] : 0.f);
        }
        g_w2s[i2] = v;
    } else if (idx < W1S_ELEMS + W2S_ELEMS + 160) {
        int i3 = idx - (W1S_ELEMS + W2S_ELEMS);
        int oj = pack_map(i3);
        g_bias[i3] = (oj >= 0) ? (b_ih[oj] + b_hh[oj]) : 0.f;
    }
}

// rotation swizzle for the f32 gate buffer (<=2-way banks both sides)
__device__ __forceinline__ int gaddr(int row, int col) {
    int c = col + ((row & 15) << 2);
    if (c >= 160) c -= 160;
    return row * 160 + c;
}

__device__ __forceinline__ float fast_tanh(float v) {
    float t = __expf(-2.f * v);
    return (1.f - t) / (1.f + t);
}

#define GLOAD16(gp, lp) __builtin_amdgcn_global_load_lds( \
    (const __attribute__((address_space(1))) void*)(gp),  \
    (__attribute__((address_space(3))) void*)(lp), 16, 0, 0)

__global__ __launch_bounds__(256, 4) void lstm_fused(
    const float* __restrict__ x, const float* __restrict__ blin,
    float* __restrict__ out)
{
    // union: phase1 {x dbuf 2x8KB @0, w1 dbuf 2x10KB @16384} = 36864B
    //        phase1.5 gates gs[64][160] f32 = 40960B ; phase2 hs[64][72] f16
    __shared__ __align__(16) char smem[40960];
    float* gs = (float*)smem;
    f16*   hs = (f16*)smem;

    const int tid  = threadIdx.x;
    const int lane = tid & 63;
    const int wv   = tid >> 6;
    const int lcol = lane & 15;
    const int l4   = lane >> 4;
    const long row0 = (long)blockIdx.x * 64;
    const int wrow = wv * 16;

    // ---- DMA slot assignment (per wave): x instrs i=2wv,2wv+1; w tiles ----
    const int wt0 = (wv < 2) ? wv * 3 : 6 + (wv - 2) * 2;  // w0:0-2 w1:3-5 w2:6,7 w3:8,9
    const int nw  = (wv < 2) ? 3 : 2;                       // per-wave DMA = 2+nw

    // x source bases for this wave's two DMA instrs (row-swizzled source)
    const int sw = ((lane & 7) ^ (lane >> 3)) << 2;         // float offset
    const float* xsrc0 = x + (row0 + (2 * wv) * 8 + (lane >> 3)) * 1024 + sw;
    const float* xsrc1 = x + (row0 + (2 * wv + 1) * 8 + (lane >> 3)) * 1024 + sw;

    char* xs0 = smem + (2 * wv) * 1024;          // +par*8192
    char* xs1 = smem + (2 * wv + 1) * 1024;

    #define STAGE(c, par) {                                                    \
        GLOAD16(xsrc0 + (c) * 32, xs0 + (par) * 8192);                         \
        GLOAD16(xsrc1 + (c) * 32, xs1 + (par) * 8192);                         \
        _Pragma("unroll")                                                      \
        for (int t = 0; t < 3; ++t)                                            \
            if (t < nw)                                                        \
                GLOAD16((const f16x8*)g_w1s + (c) * 640 + (wt0 + t) * 64 + lane, \
                        smem + 16384 + (par) * 10240 + (wt0 + t) * 1024);      \
    }

    f32x4 acc[10];
    #pragma unroll
    for (int g = 0; g < 10; ++g) acc[g] = (f32x4){0.f, 0.f, 0.f, 0.f};

    STAGE(0, 0);
    STAGE(1, 1);

    // A-read addressing (swizzled): row = wrow+lcol, units (2*l4+j)^(lcol&7)
    const int abyte = (wrow + lcol) * 128;
    const int au0 = ((2 * l4 + 0) ^ (lcol & 7)) << 4;
    const int au1 = ((2 * l4 + 1) ^ (lcol & 7)) << 4;

    for (int ks = 0; ks < 32; ++ks) {
        // wait own chunk-ks DMA done (ks+1 still in flight mid-loop)
        if (ks == 31)      asm volatile("s_waitcnt vmcnt(0)" ::: "memory");
        else if (wv < 2)   asm volatile("s_waitcnt vmcnt(5)" ::: "memory");
        else               asm volatile("s_waitcnt vmcnt(4)" ::: "memory");
        __builtin_amdgcn_sched_barrier(0);
        __builtin_amdgcn_s_barrier();          // chunk ks visible block-wide

        const int par = ks & 1;
        const char* ab = smem + par * 8192 + abyte;
        float4 qa = *(const float4*)(ab + au0);
        float4 qb = *(const float4*)(ab + au1);
        f16x8 af = { (f16)qa.x, (f16)qa.y, (f16)qa.z, (f16)qa.w,
                     (f16)qb.x, (f16)qb.y, (f16)qb.z, (f16)qb.w };
        const f16x8* wb = (const f16x8*)(smem + 16384 + par * 10240) + lane;
        #pragma unroll
        for (int g = 0; g < 10; ++g) {
            f16x8 bf = wb[g * 64];
            acc[g] = __builtin_amdgcn_mfma_f32_16x16x32_f16(af, bf, acc[g], 0, 0, 0);
        }

        asm volatile("s_waitcnt lgkmcnt(0)" ::: "memory");  // reads landed
        __builtin_amdgcn_sched_barrier(0);
        __builtin_amdgcn_s_barrier();          // safe to overwrite buf[par]
        if (ks < 30) STAGE(ks + 2, par);
    }

    // ---- phase 1.5: gates(+bias) -> swizzled LDS (overlays phase-1 bufs) ----
    #pragma unroll
    for (int g = 0; g < 10; ++g) {
        float bb = g_bias[g * 16 + lcol];
        #pragma unroll
        for (int r = 0; r < 4; ++r)
            gs[gaddr(wrow + l4 * 4 + r, g * 16 + lcol)] = acc[g][r] + bb;
    }
    __syncthreads();

    // ---- nonlinearity: thread -> (row=tid>>2, 13 cols) ----------------------
    const int nrow = tid >> 2, sub = tid & 3;
    const int c0 = sub * 13;
    float hreg[13];
    #pragma unroll
    for (int j = 0; j < 13; ++j) {
        int c = c0 + j;
        float hv = 0.f;
        if (c < 50) {
            float iv = gs[gaddr(nrow, c)];
            float gv = gs[gaddr(nrow, 50 + c)];
            float ov = gs[gaddr(nrow, 100 + c)];
            float cv = fast_tanh(gv) / (1.f + __expf(-iv));
            hv = fast_tanh(cv) / (1.f + __expf(-ov));
        }
        hreg[j] = hv;
    }
    __syncthreads();

    #pragma unroll
    for (int j = 0; j < 13; ++j)
        hs[nrow * 72 + c0 + j] = (f16)hreg[j];
    if (sub == 3) {
        #pragma unroll
        for (int c = 52; c < 64; ++c) hs[nrow * 72 + c] = (f16)0.f;
    }
    __syncthreads();

    // ---- phase 2: out = h @ W2^T + b_lin (A=W2, B=h => float4 col stores) ---
    const int hrow = wrow + lcol;
    f16x8 bh0 = *(const f16x8*)(hs + hrow * 72 + l4 * 8);
    f16x8 bh1 = *(const f16x8*)(hs + hrow * 72 + 32 + l4 * 8);
    float* orow = out + (row0 + hrow) * 1024;

    #pragma unroll 4
    for (int ct = 0; ct < 64; ++ct) {
        float4 bl = *(const float4*)(blin + ct * 16 + l4 * 4);
        f32x4 o = { bl.x, bl.y, bl.z, bl.w };
        const f16x8* w2b = g_w2s + ct * 128 + lane;
        o = __builtin_amdgcn_mfma_f32_16x16x32_f16(w2b[0],  bh0, o, 0, 0, 0);
        o = __builtin_amdgcn_mfma_f32_16x16x32_f16(w2b[64], bh1, o, 0, 0, 0);
        *(float4*)(orow + ct * 16 + l4 * 4) = *(float4*)&o;
    }
}

extern "C" void kernel_launch(void* const* d_in, const int* in_sizes, int n_in,
                              void* d_out, int out_size, void* d_ws, size_t ws_size,
                              hipStream_t stream) {
    const float* x     = (const float*)d_in[0];
    const float* W_ih  = (const float*)d_in[1];
    // d_in[2] = W_hh — provably unused (h_prev = 0)
    const float* b_ih  = (const float*)d_in[3];
    const float* b_hh  = (const float*)d_in[4];
    const float* W_lin = (const float*)d_in[5];
    const float* b_lin = (const float*)d_in[6];
    float* out = (float*)d_out;

    int prep_total = W1S_ELEMS + W2S_ELEMS + 160;
    prep_kernel<<<(prep_total + 255) / 256, 256, 0, stream>>>(
        W_ih, b_ih, b_hh, W_lin);

    lstm_fused<<<1024, 256, 0, stream>>>(x, b_lin, out);
}

// Round 9
// 171.848 us; speedup vs baseline: 1.3718x; 1.0893x over previous
//
#include <hip/hip_runtime.h>

// LSTM-cell (h0=c0=0) + Linear, fused.  out = Lin(h(x @ W_ih^T + b)), f-gate dead.
// x: [65536,1024] f32 -> out: [65536,1024] f32. HBM floor ~81us (512MB @6.3TB/s).
// R9 = R8 with the STAGE macro-hygiene bug fixed (R8's inner `for(int t...)`
// captured the outer loop var `t` in the chunk expression => weight tiles
// staged from wrong chunks; x correct => bounded garbage, absmax 1.34).
// Macro now evaluates (c),(par) once into locals; inner var renamed wti.
// This round is the REAL A/B of the DRAM-channel decorrelation theory:
//   R4-R7 invariant: ~215-245us, all pipes <10%, HBM ~1.9TB/s across three
//   schedules. Rows are 4KB-strided; all blocks sweep the same column phase
//   (chunk t, col-tile ct) in lockstep => chip-wide traffic hits the channel
//   subset selected by addr-mod-4KB => BW collapse. Fix: per-block bijective
//   rotation koff=(5*bid)&31 (phase 1), ctoff=(11*bid)&63 (phase 2).
// Structure (R7, passed): DMA-staged GEMM via global_load_lds, dbuf, counted
// per-wave vmcnt + raw s_barrier; swizzled gate exchange; reg nonlin;
// phase 2 operand-swapped MFMA with float4 stores.

typedef _Float16 f16;
typedef f16 f16x8 __attribute__((ext_vector_type(8)));
typedef float f32x4 __attribute__((ext_vector_type(4)));

#define W1S_ELEMS (32 * 10 * 64)   // f16x8 units: [ks32][gt][lane]
#define W2S_ELEMS (64 * 2 * 64)    // f16x8 units: [ct][ks2][lane]

__device__ f16x8 g_w1s[W1S_ELEMS];
__device__ f16x8 g_w2s[W2S_ELEMS];
__device__ float g_bias[160];

__device__ __forceinline__ int pack_map(int j) {
    return (j < 50) ? j : (j < 150) ? (j + 50) : -1;   // skip dead f-gate rows
}

__global__ __launch_bounds__(256) void prep_kernel(
    const float* __restrict__ W_ih, const float* __restrict__ b_ih,
    const float* __restrict__ b_hh, const float* __restrict__ W_lin)
{
    int idx = blockIdx.x * 256 + threadIdx.x;
    if (idx < W1S_ELEMS) {
        int lane = idx & 63, rest = idx >> 6;
        int gt = rest % 10, ks = rest / 10;
        int prow = gt * 16 + (lane & 15);
        int oj = pack_map(prow);
        int k0 = ks * 32 + ((lane >> 4) << 3);
        f16x8 v;
        #pragma unroll
        for (int j = 0; j < 8; ++j)
            v[j] = (f16)((oj >= 0) ? W_ih[oj * 1024 + k0 + j] : 0.f);
        g_w1s[idx] = v;
    } else if (idx < W1S_ELEMS + W2S_ELEMS) {
        int i2 = idx - W1S_ELEMS;
        int lane = i2 & 63, rest = i2 >> 6;
        int ks = rest & 1, ct = rest >> 1;
        int ocol = ct * 16 + (lane & 15);
        int k0 = ks * 32 + ((lane >> 4) << 3);
        f16x8 v;
        #pragma unroll
        for (int j = 0; j < 8; ++j) {
            int k = k0 + j;
            v[j] = (f16)((k < 50) ? W_lin[ocol * 50 + k] : 0.f);
        }
        g_w2s[i2] = v;
    } else if (idx < W1S_ELEMS + W2S_ELEMS + 160) {
        int i3 = idx - (W1S_ELEMS + W2S_ELEMS);
        int oj = pack_map(i3);
        g_bias[i3] = (oj >= 0) ? (b_ih[oj] + b_hh[oj]) : 0.f;
    }
}

// rotation swizzle for the f32 gate buffer (<=2-way banks both sides)
__device__ __forceinline__ int gaddr(int row, int col) {
    int c = col + ((row & 15) << 2);
    if (c >= 160) c -= 160;
    return row * 160 + c;
}

__device__ __forceinline__ float fast_tanh(float v) {
    float t = __expf(-2.f * v);
    return (1.f - t) / (1.f + t);
}

#define GLOAD16(gp, lp) __builtin_amdgcn_global_load_lds( \
    (const __attribute__((address_space(1))) void*)(gp),  \
    (__attribute__((address_space(3))) void*)(lp), 16, 0, 0)

__global__ __launch_bounds__(256, 4) void lstm_fused(
    const float* __restrict__ x, const float* __restrict__ blin,
    float* __restrict__ out)
{
    // union: phase1 {x dbuf 2x8KB @0, w1 dbuf 2x10KB @16384} = 36864B
    //        phase1.5 gates gs[64][160] f32 = 40960B ; phase2 hs[64][72] f16
    __shared__ __align__(16) char smem[40960];
    float* gs = (float*)smem;
    f16*   hs = (f16*)smem;

    const int tid  = threadIdx.x;
    const int lane = tid & 63;
    const int wv   = tid >> 6;
    const int lcol = lane & 15;
    const int l4   = lane >> 4;
    const long row0 = (long)blockIdx.x * 64;
    const int wrow = wv * 16;

    // per-block channel-decorrelation phases (bijective: odd multipliers)
    const int koff  = (blockIdx.x * 5) & 31;
    const int ctoff = (blockIdx.x * 11) & 63;

    // ---- DMA slot assignment (per wave): x instrs i=2wv,2wv+1; w tiles ----
    const int wt0 = (wv < 2) ? wv * 3 : 6 + (wv - 2) * 2;  // w0:0-2 w1:3-5 w2:6,7 w3:8,9
    const int nw  = (wv < 2) ? 3 : 2;                       // per-wave DMA = 2+nw

    // x source bases for this wave's two DMA instrs (row-swizzled source)
    const int sw = ((lane & 7) ^ (lane >> 3)) << 2;         // float offset
    const float* xsrc0 = x + (row0 + (2 * wv) * 8 + (lane >> 3)) * 1024 + sw;
    const float* xsrc1 = x + (row0 + (2 * wv + 1) * 8 + (lane >> 3)) * 1024 + sw;

    char* xs0 = smem + (2 * wv) * 1024;          // +par*8192
    char* xs1 = smem + (2 * wv + 1) * 1024;

    // hygiene: evaluate args ONCE into locals; inner loop var is wti (R8 bug:
    // inner `t` captured the outer loop variable in the (c) expansion)
    #define STAGE(c, par) do {                                                 \
        const int c_ = (c);                                                    \
        const int p_ = (par);                                                  \
        GLOAD16(xsrc0 + c_ * 32, xs0 + p_ * 8192);                             \
        GLOAD16(xsrc1 + c_ * 32, xs1 + p_ * 8192);                             \
        _Pragma("unroll")                                                      \
        for (int wti = 0; wti < 3; ++wti)                                      \
            if (wti < nw)                                                      \
                GLOAD16((const f16x8*)g_w1s + c_ * 640 + (wt0 + wti) * 64 + lane, \
                        smem + 16384 + p_ * 10240 + (wt0 + wti) * 1024);       \
    } while (0)

    f32x4 acc[10];
    #pragma unroll
    for (int g = 0; g < 10; ++g) acc[g] = (f32x4){0.f, 0.f, 0.f, 0.f};

    STAGE(koff, 0);
    STAGE((koff + 1) & 31, 1);

    // A-read addressing (swizzled): row = wrow+lcol, units (2*l4+j)^(lcol&7)
    const int abyte = (wrow + lcol) * 128;
    const int au0 = ((2 * l4 + 0) ^ (lcol & 7)) << 4;
    const int au1 = ((2 * l4 + 1) ^ (lcol & 7)) << 4;

    for (int t = 0; t < 32; ++t) {
        // wait own chunk-t DMA done (chunk t+1 still in flight mid-loop)
        if (t == 31)       asm volatile("s_waitcnt vmcnt(0)" ::: "memory");
        else if (wv < 2)   asm volatile("s_waitcnt vmcnt(5)" ::: "memory");
        else               asm volatile("s_waitcnt vmcnt(4)" ::: "memory");
        __builtin_amdgcn_sched_barrier(0);
        __builtin_amdgcn_s_barrier();          // chunk t visible block-wide

        const int par = t & 1;
        const char* ab = smem + par * 8192 + abyte;
        float4 qa = *(const float4*)(ab + au0);
        float4 qb = *(const float4*)(ab + au1);
        f16x8 af = { (f16)qa.x, (f16)qa.y, (f16)qa.z, (f16)qa.w,
                     (f16)qb.x, (f16)qb.y, (f16)qb.z, (f16)qb.w };
        const f16x8* wb = (const f16x8*)(smem + 16384 + par * 10240) + lane;
        #pragma unroll
        for (int g = 0; g < 10; ++g) {
            f16x8 bf = wb[g * 64];
            acc[g] = __builtin_amdgcn_mfma_f32_16x16x32_f16(af, bf, acc[g], 0, 0, 0);
        }

        asm volatile("s_waitcnt lgkmcnt(0)" ::: "memory");  // reads landed
        __builtin_amdgcn_sched_barrier(0);
        __builtin_amdgcn_s_barrier();          // safe to overwrite buf[par]
        if (t < 30) STAGE((t + 2 + koff) & 31, par);
    }

    // ---- phase 1.5: gates(+bias) -> swizzled LDS (overlays phase-1 bufs) ----
    #pragma unroll
    for (int g = 0; g < 10; ++g) {
        float bb = g_bias[g * 16 + lcol];
        #pragma unroll
        for (int r = 0; r < 4; ++r)
            gs[gaddr(wrow + l4 * 4 + r, g * 16 + lcol)] = acc[g][r] + bb;
    }
    __syncthreads();

    // ---- nonlinearity: thread -> (row=tid>>2, 13 cols) ----------------------
    const int nrow = tid >> 2, sub = tid & 3;
    const int c0 = sub * 13;
    float hreg[13];
    #pragma unroll
    for (int j = 0; j < 13; ++j) {
        int c = c0 + j;
        float hv = 0.f;
        if (c < 50) {
            float iv = gs[gaddr(nrow, c)];
            float gv = gs[gaddr(nrow, 50 + c)];
            float ov = gs[gaddr(nrow, 100 + c)];
            float cv = fast_tanh(gv) / (1.f + __expf(-iv));
            hv = fast_tanh(cv) / (1.f + __expf(-ov));
        }
        hreg[j] = hv;
    }
    __syncthreads();

    #pragma unroll
    for (int j = 0; j < 13; ++j)
        hs[nrow * 72 + c0 + j] = (f16)hreg[j];
    if (sub == 3) {
        #pragma unroll
        for (int c = 52; c < 64; ++c) hs[nrow * 72 + c] = (f16)0.f;
    }
    __syncthreads();

    // ---- phase 2: out = h @ W2^T + b_lin (A=W2, B=h => float4 col stores) ---
    const int hrow = wrow + lcol;
    f16x8 bh0 = *(const f16x8*)(hs + hrow * 72 + l4 * 8);
    f16x8 bh1 = *(const f16x8*)(hs + hrow * 72 + 32 + l4 * 8);
    float* orow = out + (row0 + hrow) * 1024;

    #pragma unroll 4
    for (int t2 = 0; t2 < 64; ++t2) {
        int ct = (t2 + ctoff) & 63;
        float4 bl = *(const float4*)(blin + ct * 16 + l4 * 4);
        f32x4 o = { bl.x, bl.y, bl.z, bl.w };
        const f16x8* w2b = g_w2s + ct * 128 + lane;
        o = __builtin_amdgcn_mfma_f32_16x16x32_f16(w2b[0],  bh0, o, 0, 0, 0);
        o = __builtin_amdgcn_mfma_f32_16x16x32_f16(w2b[64], bh1, o, 0, 0, 0);
        *(float4*)(orow + ct * 16 + l4 * 4) = *(float4*)&o;
    }
}

extern "C" void kernel_launch(void* const* d_in, const int* in_sizes, int n_in,
                              void* d_out, int out_size, void* d_ws, size_t ws_size,
                              hipStream_t stream) {
    const float* x     = (const float*)d_in[0];
    const float* W_ih  = (const float*)d_in[1];
    // d_in[2] = W_hh — provably unused (h_prev = 0)
    const float* b_ih  = (const float*)d_in[3];
    const float* b_hh  = (const float*)d_in[4];
    const float* W_lin = (const float*)d_in[5];
    const float* b_lin = (const float*)d_in[6];
    float* out = (float*)d_out;

    int prep_total = W1S_ELEMS + W2S_ELEMS + 160;
    prep_kernel<<<(prep_total + 255) / 256, 256, 0, stream>>>(
        W_ih, b_ih, b_hh, W_lin);

    lstm_fused<<<1024, 256, 0, stream>>>(x, b_lin, out);
}

// Round 10
// 171.097 us; speedup vs baseline: 1.3778x; 1.0044x over previous
//
#include <hip/hip_runtime.h>

// LSTM-cell (h0=c0=0) + Linear, fused.  out = Lin(h(x @ W_ih^T + b)), f-gate dead.
// x: [65536,1024] f32 -> out: [65536,1024] f32. HBM floor ~64-81us.
// R10 = R9 + co-resident channel-phase fix (the one change under test):
//   R9's koff=(5*bid)&31, ctoff=(11*bid)&63 are ≡ for bid,bid+256,bid+512,
//   bid+768 — exactly the 4 blocks co-resident on one CU (1024 blocks = one
//   fully-resident generation). So each CU's whole stream had ONE phase; the
//   intended DRAM-channel spread never happened at co-residency level.
//   Fix: + (bid>>8)*8 (mod 32) and + (bid>>8)*16 (mod 64); phase 2 also
//   offsets per wave (+wv*16, waves barrier-free there).
// Structure (R7/R9, passed @172us): DMA-staged GEMM via global_load_lds,
// dbuf, counted per-wave vmcnt + raw s_barrier; swizzled gate exchange;
// reg nonlin; phase 2 operand-swapped MFMA with float4 stores.

typedef _Float16 f16;
typedef f16 f16x8 __attribute__((ext_vector_type(8)));
typedef float f32x4 __attribute__((ext_vector_type(4)));

#define W1S_ELEMS (32 * 10 * 64)   // f16x8 units: [ks32][gt][lane]
#define W2S_ELEMS (64 * 2 * 64)    // f16x8 units: [ct][ks2][lane]

__device__ f16x8 g_w1s[W1S_ELEMS];
__device__ f16x8 g_w2s[W2S_ELEMS];
__device__ float g_bias[160];

__device__ __forceinline__ int pack_map(int j) {
    return (j < 50) ? j : (j < 150) ? (j + 50) : -1;   // skip dead f-gate rows
}

__global__ __launch_bounds__(256) void prep_kernel(
    const float* __restrict__ W_ih, const float* __restrict__ b_ih,
    const float* __restrict__ b_hh, const float* __restrict__ W_lin)
{
    int idx = blockIdx.x * 256 + threadIdx.x;
    if (idx < W1S_ELEMS) {
        int lane = idx & 63, rest = idx >> 6;
        int gt = rest % 10, ks = rest / 10;
        int prow = gt * 16 + (lane & 15);
        int oj = pack_map(prow);
        int k0 = ks * 32 + ((lane >> 4) << 3);
        f16x8 v;
        #pragma unroll
        for (int j = 0; j < 8; ++j)
            v[j] = (f16)((oj >= 0) ? W_ih[oj * 1024 + k0 + j] : 0.f);
        g_w1s[idx] = v;
    } else if (idx < W1S_ELEMS + W2S_ELEMS) {
        int i2 = idx - W1S_ELEMS;
        int lane = i2 & 63, rest = i2 >> 6;
        int ks = rest & 1, ct = rest >> 1;
        int ocol = ct * 16 + (lane & 15);
        int k0 = ks * 32 + ((lane >> 4) << 3);
        f16x8 v;
        #pragma unroll
        for (int j = 0; j < 8; ++j) {
            int k = k0 + j;
            v[j] = (f16)((k < 50) ? W_lin[ocol * 50 + k] : 0.f);
        }
        g_w2s[i2] = v;
    } else if (idx < W1S_ELEMS + W2S_ELEMS + 160) {
        int i3 = idx - (W1S_ELEMS + W2S_ELEMS);
        int oj = pack_map(i3);
        g_bias[i3] = (oj >= 0) ? (b_ih[oj] + b_hh[oj]) : 0.f;
    }
}

// rotation swizzle for the f32 gate buffer (<=2-way banks both sides)
__device__ __forceinline__ int gaddr(int row, int col) {
    int c = col + ((row & 15) << 2);
    if (c >= 160) c -= 160;
    return row * 160 + c;
}

__device__ __forceinline__ float fast_tanh(float v) {
    float t = __expf(-2.f * v);
    return (1.f - t) / (1.f + t);
}

#define GLOAD16(gp, lp) __builtin_amdgcn_global_load_lds( \
    (const __attribute__((address_space(1))) void*)(gp),  \
    (__attribute__((address_space(3))) void*)(lp), 16, 0, 0)

__global__ __launch_bounds__(256, 4) void lstm_fused(
    const float* __restrict__ x, const float* __restrict__ blin,
    float* __restrict__ out)
{
    // union: phase1 {x dbuf 2x8KB @0, w1 dbuf 2x10KB @16384} = 36864B
    //        phase1.5 gates gs[64][160] f32 = 40960B ; phase2 hs[64][72] f16
    __shared__ __align__(16) char smem[40960];
    float* gs = (float*)smem;
    f16*   hs = (f16*)smem;

    const int tid  = threadIdx.x;
    const int lane = tid & 63;
    const int wv   = tid >> 6;
    const int lcol = lane & 15;
    const int l4   = lane >> 4;
    const long row0 = (long)blockIdx.x * 64;
    const int wrow = wv * 16;

    // channel-decorrelation phases: linear term spreads neighbors; the
    // (bid>>8) term spreads the 4 CO-RESIDENT blocks of one CU (stride 256,
    // where any linear-in-bid term vanishes mod 32/64).
    const int bid   = blockIdx.x;
    const int koff  = (bid * 5 + (bid >> 8) * 8) & 31;
    const int ctoff = ((bid * 11 + (bid >> 8) * 16) & 63) + wv * 16;

    // ---- DMA slot assignment (per wave): x instrs i=2wv,2wv+1; w tiles ----
    const int wt0 = (wv < 2) ? wv * 3 : 6 + (wv - 2) * 2;  // w0:0-2 w1:3-5 w2:6,7 w3:8,9
    const int nw  = (wv < 2) ? 3 : 2;                       // per-wave DMA = 2+nw

    // x source bases for this wave's two DMA instrs (row-swizzled source)
    const int sw = ((lane & 7) ^ (lane >> 3)) << 2;         // float offset
    const float* xsrc0 = x + (row0 + (2 * wv) * 8 + (lane >> 3)) * 1024 + sw;
    const float* xsrc1 = x + (row0 + (2 * wv + 1) * 8 + (lane >> 3)) * 1024 + sw;

    char* xs0 = smem + (2 * wv) * 1024;          // +par*8192
    char* xs1 = smem + (2 * wv + 1) * 1024;

    // hygiene: evaluate args ONCE into locals; inner loop var is wti
    #define STAGE(c, par) do {                                                 \
        const int c_ = (c);                                                    \
        const int p_ = (par);                                                  \
        GLOAD16(xsrc0 + c_ * 32, xs0 + p_ * 8192);                             \
        GLOAD16(xsrc1 + c_ * 32, xs1 + p_ * 8192);                             \
        _Pragma("unroll")                                                      \
        for (int wti = 0; wti < 3; ++wti)                                      \
            if (wti < nw)                                                      \
                GLOAD16((const f16x8*)g_w1s + c_ * 640 + (wt0 + wti) * 64 + lane, \
                        smem + 16384 + p_ * 10240 + (wt0 + wti) * 1024);       \
    } while (0)

    f32x4 acc[10];
    #pragma unroll
    for (int g = 0; g < 10; ++g) acc[g] = (f32x4){0.f, 0.f, 0.f, 0.f};

    STAGE(koff, 0);
    STAGE((koff + 1) & 31, 1);

    // A-read addressing (swizzled): row = wrow+lcol, units (2*l4+j)^(lcol&7)
    const int abyte = (wrow + lcol) * 128;
    const int au0 = ((2 * l4 + 0) ^ (lcol & 7)) << 4;
    const int au1 = ((2 * l4 + 1) ^ (lcol & 7)) << 4;

    for (int t = 0; t < 32; ++t) {
        // wait own chunk-t DMA done (chunk t+1 still in flight mid-loop)
        if (t == 31)       asm volatile("s_waitcnt vmcnt(0)" ::: "memory");
        else if (wv < 2)   asm volatile("s_waitcnt vmcnt(5)" ::: "memory");
        else               asm volatile("s_waitcnt vmcnt(4)" ::: "memory");
        __builtin_amdgcn_sched_barrier(0);
        __builtin_amdgcn_s_barrier();          // chunk t visible block-wide

        const int par = t & 1;
        const char* ab = smem + par * 8192 + abyte;
        float4 qa = *(const float4*)(ab + au0);
        float4 qb = *(const float4*)(ab + au1);
        f16x8 af = { (f16)qa.x, (f16)qa.y, (f16)qa.z, (f16)qa.w,
                     (f16)qb.x, (f16)qb.y, (f16)qb.z, (f16)qb.w };
        const f16x8* wb = (const f16x8*)(smem + 16384 + par * 10240) + lane;
        #pragma unroll
        for (int g = 0; g < 10; ++g) {
            f16x8 bf = wb[g * 64];
            acc[g] = __builtin_amdgcn_mfma_f32_16x16x32_f16(af, bf, acc[g], 0, 0, 0);
        }

        asm volatile("s_waitcnt lgkmcnt(0)" ::: "memory");  // reads landed
        __builtin_amdgcn_sched_barrier(0);
        __builtin_amdgcn_s_barrier();          // safe to overwrite buf[par]
        if (t < 30) STAGE((t + 2 + koff) & 31, par);
    }

    // ---- phase 1.5: gates(+bias) -> swizzled LDS (overlays phase-1 bufs) ----
    #pragma unroll
    for (int g = 0; g < 10; ++g) {
        float bb = g_bias[g * 16 + lcol];
        #pragma unroll
        for (int r = 0; r < 4; ++r)
            gs[gaddr(wrow + l4 * 4 + r, g * 16 + lcol)] = acc[g][r] + bb;
    }
    __syncthreads();

    // ---- nonlinearity: thread -> (row=tid>>2, 13 cols) ----------------------
    const int nrow = tid >> 2, sub = tid & 3;
    const int c0 = sub * 13;
    float hreg[13];
    #pragma unroll
    for (int j = 0; j < 13; ++j) {
        int c = c0 + j;
        float hv = 0.f;
        if (c < 50) {
            float iv = gs[gaddr(nrow, c)];
            float gv = gs[gaddr(nrow, 50 + c)];
            float ov = gs[gaddr(nrow, 100 + c)];
            float cv = fast_tanh(gv) / (1.f + __expf(-iv));
            hv = fast_tanh(cv) / (1.f + __expf(-ov));
        }
        hreg[j] = hv;
    }
    __syncthreads();

    #pragma unroll
    for (int j = 0; j < 13; ++j)
        hs[nrow * 72 + c0 + j] = (f16)hreg[j];
    if (sub == 3) {
        #pragma unroll
        for (int c = 52; c < 64; ++c) hs[nrow * 72 + c] = (f16)0.f;
    }
    __syncthreads();

    // ---- phase 2: out = h @ W2^T + b_lin (A=W2, B=h => float4 col stores) ---
    const int hrow = wrow + lcol;
    f16x8 bh0 = *(const f16x8*)(hs + hrow * 72 + l4 * 8);
    f16x8 bh1 = *(const f16x8*)(hs + hrow * 72 + 32 + l4 * 8);
    float* orow = out + (row0 + hrow) * 1024;

    #pragma unroll 4
    for (int t2 = 0; t2 < 64; ++t2) {
        int ct = (t2 + ctoff) & 63;
        float4 bl = *(const float4*)(blin + ct * 16 + l4 * 4);
        f32x4 o = { bl.x, bl.y, bl.z, bl.w };
        const f16x8* w2b = g_w2s + ct * 128 + lane;
        o = __builtin_amdgcn_mfma_f32_16x16x32_f16(w2b[0],  bh0, o, 0, 0, 0);
        o = __builtin_amdgcn_mfma_f32_16x16x32_f16(w2b[64], bh1, o, 0, 0, 0);
        *(float4*)(orow + ct * 16 + l4 * 4) = *(float4*)&o;
    }
}

extern "C" void kernel_launch(void* const* d_in, const int* in_sizes, int n_in,
                              void* d_out, int out_size, void* d_ws, size_t ws_size,
                              hipStream_t stream) {
    const float* x     = (const float*)d_in[0];
    const float* W_ih  = (const float*)d_in[1];
    // d_in[2] = W_hh — provably unused (h_prev = 0)
    const float* b_ih  = (const float*)d_in[3];
    const float* b_hh  = (const float*)d_in[4];
    const float* W_lin = (const float*)d_in[5];
    const float* b_lin = (const float*)d_in[6];
    float* out = (float*)d_out;

    int prep_total = W1S_ELEMS + W2S_ELEMS + 160;
    prep_kernel<<<(prep_total + 255) / 256, 256, 0, stream>>>(
        W_ih, b_ih, b_hh, W_lin);

    lstm_fused<<<1024, 256, 0, stream>>>(x, b_lin, out);
}

// Round 11
// 163.303 us; speedup vs baseline: 1.4436x; 1.0477x over previous
//
#include <hip/hip_runtime.h>

// LSTM-cell (h0=c0=0) + Linear.  out = Lin(h(x @ W_ih^T + b)), f-gate dead.
// x: [65536,1024] f32 -> out: [65536,1024] f32. HBM floor ~81us total.
// R11: SPLIT for rocprof attribution (R4-R10 invariant: ~171-245us, all pipes
// <12%, HBM ~2.2TB/s across five schedule/decorrelation variants; cannot
// attribute read vs write path inside one fused dispatch).
//   A lstm_gates: R10 phase1+nonlin (proven), writes h f16 [65536,64] = 8MB
//     to __device__ g_h. Read-dominated: 256MB in / 8MB out, floor ~42us.
//   B lstm_lin:   out = h @ W2^T + blin. 32 rows/block, grid 2048 = 8
//     blocks/CU (full 32-wave occupancy), h in padded LDS, W2/blin L2-hot,
//     R6-proven swap-MFMA + float4 stores. Write-dominated: floor ~42us.
// Split overhead: +16MB traffic (3%). Whichever kernel exceeds its floor 2x
// is the target next round.

typedef _Float16 f16;
typedef f16 f16x8 __attribute__((ext_vector_type(8)));
typedef float f32x4 __attribute__((ext_vector_type(4)));

#define W1S_ELEMS (32 * 10 * 64)   // f16x8 units: [ks32][gt][lane]
#define W2S_ELEMS (64 * 2 * 64)    // f16x8 units: [ct][ks2][lane]

__device__ f16x8 g_w1s[W1S_ELEMS];
__device__ f16x8 g_w2s[W2S_ELEMS];
__device__ float g_bias[160];
__device__ f16   g_h[65536L * 64];   // intermediate h (8MB)

__device__ __forceinline__ int pack_map(int j) {
    return (j < 50) ? j : (j < 150) ? (j + 50) : -1;   // skip dead f-gate rows
}

__global__ __launch_bounds__(256) void prep_kernel(
    const float* __restrict__ W_ih, const float* __restrict__ b_ih,
    const float* __restrict__ b_hh, const float* __restrict__ W_lin)
{
    int idx = blockIdx.x * 256 + threadIdx.x;
    if (idx < W1S_ELEMS) {
        int lane = idx & 63, rest = idx >> 6;
        int gt = rest % 10, ks = rest / 10;
        int prow = gt * 16 + (lane & 15);
        int oj = pack_map(prow);
        int k0 = ks * 32 + ((lane >> 4) << 3);
        f16x8 v;
        #pragma unroll
        for (int j = 0; j < 8; ++j)
            v[j] = (f16)((oj >= 0) ? W_ih[oj * 1024 + k0 + j] : 0.f);
        g_w1s[idx] = v;
    } else if (idx < W1S_ELEMS + W2S_ELEMS) {
        int i2 = idx - W1S_ELEMS;
        int lane = i2 & 63, rest = i2 >> 6;
        int ks = rest & 1, ct = rest >> 1;
        int ocol = ct * 16 + (lane & 15);
        int k0 = ks * 32 + ((lane >> 4) << 3);
        f16x8 v;
        #pragma unroll
        for (int j = 0; j < 8; ++j) {
            int k = k0 + j;
            v[j] = (f16)((k < 50) ? W_lin[ocol * 50 + k] : 0.f);
        }
        g_w2s[i2] = v;
    } else if (idx < W1S_ELEMS + W2S_ELEMS + 160) {
        int i3 = idx - (W1S_ELEMS + W2S_ELEMS);
        int oj = pack_map(i3);
        g_bias[i3] = (oj >= 0) ? (b_ih[oj] + b_hh[oj]) : 0.f;
    }
}

// rotation swizzle for the f32 gate buffer (<=2-way banks both sides)
__device__ __forceinline__ int gaddr(int row, int col) {
    int c = col + ((row & 15) << 2);
    if (c >= 160) c -= 160;
    return row * 160 + c;
}

__device__ __forceinline__ float fast_tanh(float v) {
    float t = __expf(-2.f * v);
    return (1.f - t) / (1.f + t);
}

#define GLOAD16(gp, lp) __builtin_amdgcn_global_load_lds( \
    (const __attribute__((address_space(1))) void*)(gp),  \
    (__attribute__((address_space(3))) void*)(lp), 16, 0, 0)

// ---- kernel A: x -> h (R10 phase 1 + nonlin, proven; h to g_h) -------------
__global__ __launch_bounds__(256, 4) void lstm_gates(const float* __restrict__ x)
{
    __shared__ __align__(16) char smem[40960];
    float* gs = (float*)smem;
    f16*   hs = (f16*)smem;

    const int tid  = threadIdx.x;
    const int lane = tid & 63;
    const int wv   = tid >> 6;
    const int lcol = lane & 15;
    const int l4   = lane >> 4;
    const long row0 = (long)blockIdx.x * 64;
    const int wrow = wv * 16;

    const int bid   = blockIdx.x;
    const int koff  = (bid * 5 + (bid >> 8) * 8) & 31;

    const int wt0 = (wv < 2) ? wv * 3 : 6 + (wv - 2) * 2;
    const int nw  = (wv < 2) ? 3 : 2;

    const int sw = ((lane & 7) ^ (lane >> 3)) << 2;
    const float* xsrc0 = x + (row0 + (2 * wv) * 8 + (lane >> 3)) * 1024 + sw;
    const float* xsrc1 = x + (row0 + (2 * wv + 1) * 8 + (lane >> 3)) * 1024 + sw;

    char* xs0 = smem + (2 * wv) * 1024;
    char* xs1 = smem + (2 * wv + 1) * 1024;

    #define STAGE(c, par) do {                                                 \
        const int c_ = (c);                                                    \
        const int p_ = (par);                                                  \
        GLOAD16(xsrc0 + c_ * 32, xs0 + p_ * 8192);                             \
        GLOAD16(xsrc1 + c_ * 32, xs1 + p_ * 8192);                             \
        _Pragma("unroll")                                                      \
        for (int wti = 0; wti < 3; ++wti)                                      \
            if (wti < nw)                                                      \
                GLOAD16((const f16x8*)g_w1s + c_ * 640 + (wt0 + wti) * 64 + lane, \
                        smem + 16384 + p_ * 10240 + (wt0 + wti) * 1024);       \
    } while (0)

    f32x4 acc[10];
    #pragma unroll
    for (int g = 0; g < 10; ++g) acc[g] = (f32x4){0.f, 0.f, 0.f, 0.f};

    STAGE(koff, 0);
    STAGE((koff + 1) & 31, 1);

    const int abyte = (wrow + lcol) * 128;
    const int au0 = ((2 * l4 + 0) ^ (lcol & 7)) << 4;
    const int au1 = ((2 * l4 + 1) ^ (lcol & 7)) << 4;

    for (int t = 0; t < 32; ++t) {
        if (t == 31)       asm volatile("s_waitcnt vmcnt(0)" ::: "memory");
        else if (wv < 2)   asm volatile("s_waitcnt vmcnt(5)" ::: "memory");
        else               asm volatile("s_waitcnt vmcnt(4)" ::: "memory");
        __builtin_amdgcn_sched_barrier(0);
        __builtin_amdgcn_s_barrier();

        const int par = t & 1;
        const char* ab = smem + par * 8192 + abyte;
        float4 qa = *(const float4*)(ab + au0);
        float4 qb = *(const float4*)(ab + au1);
        f16x8 af = { (f16)qa.x, (f16)qa.y, (f16)qa.z, (f16)qa.w,
                     (f16)qb.x, (f16)qb.y, (f16)qb.z, (f16)qb.w };
        const f16x8* wb = (const f16x8*)(smem + 16384 + par * 10240) + lane;
        #pragma unroll
        for (int g = 0; g < 10; ++g) {
            f16x8 bf = wb[g * 64];
            acc[g] = __builtin_amdgcn_mfma_f32_16x16x32_f16(af, bf, acc[g], 0, 0, 0);
        }

        asm volatile("s_waitcnt lgkmcnt(0)" ::: "memory");
        __builtin_amdgcn_sched_barrier(0);
        __builtin_amdgcn_s_barrier();
        if (t < 30) STAGE((t + 2 + koff) & 31, par);
    }

    // gates(+bias) -> swizzled LDS exchange
    #pragma unroll
    for (int g = 0; g < 10; ++g) {
        float bb = g_bias[g * 16 + lcol];
        #pragma unroll
        for (int r = 0; r < 4; ++r)
            gs[gaddr(wrow + l4 * 4 + r, g * 16 + lcol)] = acc[g][r] + bb;
    }
    __syncthreads();

    const int nrow = tid >> 2, sub = tid & 3;
    const int c0 = sub * 13;
    float hreg[13];
    #pragma unroll
    for (int j = 0; j < 13; ++j) {
        int c = c0 + j;
        float hv = 0.f;
        if (c < 50) {
            float iv = gs[gaddr(nrow, c)];
            float gv = gs[gaddr(nrow, 50 + c)];
            float ov = gs[gaddr(nrow, 100 + c)];
            float cv = fast_tanh(gv) / (1.f + __expf(-iv));
            hv = fast_tanh(cv) / (1.f + __expf(-ov));
        }
        hreg[j] = hv;
    }
    __syncthreads();

    #pragma unroll
    for (int j = 0; j < 13; ++j)
        hs[nrow * 72 + c0 + j] = (f16)hreg[j];
    if (sub == 3) {
        #pragma unroll
        for (int c = 52; c < 64; ++c) hs[nrow * 72 + c] = (f16)0.f;
    }
    __syncthreads();

    // h tile -> g_h (vectorized 2x16B per thread, coalesced)
    {
        const int hr = tid >> 2;                 // 0..63
        const int uu = (tid & 3) * 2;            // f16x8 unit 0,2,4,6
        f16x8 v0 = *(const f16x8*)(hs + hr * 72 + uu * 8);
        f16x8 v1 = *(const f16x8*)(hs + hr * 72 + uu * 8 + 8);
        *(f16x8*)(g_h + (row0 + hr) * 64 + uu * 8)     = v0;
        *(f16x8*)(g_h + (row0 + hr) * 64 + uu * 8 + 8) = v1;
    }
}

// ---- kernel B: h -> out (skinny GEMM K=64, write-dominated) ----------------
__global__ __launch_bounds__(256, 8) void lstm_lin(
    const float* __restrict__ blin, float* __restrict__ out)
{
    __shared__ __align__(16) f16 hs_l[32 * 72];   // padded: 144B stride, 2-way banks

    const int tid  = threadIdx.x;
    const int lane = tid & 63;
    const int wv   = tid >> 6;
    const int lcol = lane & 15;
    const int l4   = lane >> 4;
    const long r0  = (long)blockIdx.x * 32;

    {   // load h tile: 32x64 f16, one f16x8 per thread
        int row = tid >> 3, u = tid & 7;
        *(f16x8*)(hs_l + row * 72 + u * 8) =
            *(const f16x8*)(g_h + (r0 + row) * 64 + u * 8);
    }
    __syncthreads();

    f16x8 bh[2][2];
    #pragma unroll
    for (int rt = 0; rt < 2; ++rt)
        #pragma unroll
        for (int k2 = 0; k2 < 2; ++k2)
            bh[rt][k2] = *(const f16x8*)(hs_l + (rt * 16 + lcol) * 72 + k2 * 32 + l4 * 8);

    const int ct0  = wv * 16;                    // wave owns 256 out cols
    const int boff = blockIdx.x & 15;            // store-phase decorrelation
    #pragma unroll 4
    for (int i = 0; i < 16; ++i) {
        int ct = ct0 + ((i + boff) & 15);
        float4 bl = *(const float4*)(blin + ct * 16 + l4 * 4);
        const f16x8* w2b = g_w2s + ct * 128 + lane;
        f16x8 w20 = w2b[0], w21 = w2b[64];
        f32x4 o0 = { bl.x, bl.y, bl.z, bl.w };
        f32x4 o1 = o0;
        o0 = __builtin_amdgcn_mfma_f32_16x16x32_f16(w20, bh[0][0], o0, 0, 0, 0);
        o0 = __builtin_amdgcn_mfma_f32_16x16x32_f16(w21, bh[0][1], o0, 0, 0, 0);
        o1 = __builtin_amdgcn_mfma_f32_16x16x32_f16(w20, bh[1][0], o1, 0, 0, 0);
        o1 = __builtin_amdgcn_mfma_f32_16x16x32_f16(w21, bh[1][1], o1, 0, 0, 0);
        *(float4*)(out + (r0 + lcol) * 1024 + ct * 16 + l4 * 4)        = *(float4*)&o0;
        *(float4*)(out + (r0 + 16 + lcol) * 1024 + ct * 16 + l4 * 4)   = *(float4*)&o1;
    }
}

extern "C" void kernel_launch(void* const* d_in, const int* in_sizes, int n_in,
                              void* d_out, int out_size, void* d_ws, size_t ws_size,
                              hipStream_t stream) {
    const float* x     = (const float*)d_in[0];
    const float* W_ih  = (const float*)d_in[1];
    // d_in[2] = W_hh — provably unused (h_prev = 0)
    const float* b_ih  = (const float*)d_in[3];
    const float* b_hh  = (const float*)d_in[4];
    const float* W_lin = (const float*)d_in[5];
    const float* b_lin = (const float*)d_in[6];
    float* out = (float*)d_out;

    int prep_total = W1S_ELEMS + W2S_ELEMS + 160;
    prep_kernel<<<(prep_total + 255) / 256, 256, 0, stream>>>(
        W_ih, b_ih, b_hh, W_lin);

    lstm_gates<<<1024, 256, 0, stream>>>(x);
    lstm_lin<<<2048, 256, 0, stream>>>(b_lin, out);
}